// Round 8
// baseline (2202.412 us; speedup 1.0000x reference)
//
#include <hip/hip_runtime.h>
#include <math.h>

// ---------------------------------------------------------------------------
// R2P2_Dynamic round 5: single change vs round 4 — NBLK 256 -> 512 so TWO
// blocks co-reside per CU (grid was the occupancy cap: 256 blocks on 256
// CUs = 1 block/CU; barrier stalls had nothing to overlap with).
// LDS 2x62KB = 124KB <= 160KB; 128 VGPR allows 16 waves/CU (m69).
// ---------------------------------------------------------------------------

typedef _Float16 f16;
typedef _Float16 f16x8 __attribute__((ext_vector_type(8)));
typedef float    f32x4 __attribute__((ext_vector_type(4)));

constexpr int BTOT = 131072;
constexpr int TSTEPS = 30;
constexpr int H  = 150;
constexpr int SD = 50;
constexpr int BT = 16;
constexpr int NT = 512;
constexpr int NBLK = 512;                  // <-- was 256
constexpr int NGRP = BTOT / (NBLK * BT);   // 16

constexpr int HP = 160;    // padded per-gate width
constexpr int NP = 480;    // padded 3H
constexpr int AHS = 232;   // f16 A-row stride: [h 0..149 |pad| static 160..209 |pad]
constexpr int O1S = 72;    // padded o1 / W2 row stride (f16)

// workspace byte offsets
constexpr int WS_WIHT  = 0;          // 30*480*2 floats = 115200 B
constexpr int WS_BFRAG = 115200;     // 10*3*5*512 f16   = 153600 B

constexpr int SIG_OFF = TSTEPS * BTOT * 2;
constexpr int X_OFF   = SIG_OFF + TSTEPS * BTOT * 4;

__device__ __forceinline__ float fexp(float x)  { return __builtin_amdgcn_exp2f(x * 1.44269504f); }
__device__ __forceinline__ float sigm(float x)  { return __builtin_amdgcn_rcpf(1.f + __builtin_amdgcn_exp2f(-1.44269504f * x)); }
__device__ __forceinline__ float tanh_(float x) { return fmaf(-2.f, __builtin_amdgcn_rcpf(1.f + __builtin_amdgcn_exp2f(2.88539008f * x)), 1.f); }
__device__ __forceinline__ float softplus_(float v) {
    float e = __builtin_amdgcn_exp2f(-1.44269504f * fabsf(v));
    return fmaxf(v, 0.f) + 0.69314718f * __builtin_amdgcn_logf(1.f + e);
}

// --- prep1: W_ih [450][60] -> ws [30][480][2] fp32 (padded, gate-major) ----
__global__ void r2p2_prep(const float* __restrict__ Wih, float* __restrict__ ws) {
    int id = blockIdx.x * 256 + threadIdx.x;
    if (id >= TSTEPS * NP) return;
    int s = id / NP, tp = id - s * NP;
    int g = tp / HP, off = tp - g * HP;
    float2 v = make_float2(0.f, 0.f);
    if (off < H) {
        const float* row = Wih + (g * H + off) * (2 * TSTEPS);
        v.x = row[2 * s];
        v.y = row[2 * s + 1];
    }
    ((float2*)ws)[id] = v;
}

// --- prep2: W_hh -> fragment-order f16 [(k*3+g)*5+kk][lane][8] --------------
__global__ void r2p2_prep2(const float* __restrict__ Whh, f16* __restrict__ wsB) {
    int id = blockIdx.x * 256 + threadIdx.x;      // over 10*3*5*64 = 9600
    if (id >= 9600) return;
    int lane = id & 63, rest = id >> 6;           // rest = (k*3+g)*5+kk
    int kk = rest % 5, kg = rest / 5;
    int g = kg % 3, k = kg / 3;
    int lr = lane & 15, lq = lane >> 4;
    int nr = k * 16 + lr;
    f16x8 v;
    #pragma unroll
    for (int j = 0; j < 8; ++j) {
        int cc = kk * 32 + lq * 8 + j;
        float x = (nr < H && cc < H) ? Whh[(g * H + nr) * H + cc] : 0.f;
        v[j] = (f16)x;
    }
    *(f16x8*)(wsB + (size_t)id * 8) = v;
}

__global__ __launch_bounds__(NT, 2) void r2p2_main(
    const float* __restrict__ statp, const float* __restrict__ initv,
    const float* __restrict__ initp, const float* __restrict__ zp,
    const float* __restrict__ bih,   const float* __restrict__ bhh,
    const float* __restrict__ W1,    const float* __restrict__ b1,
    const float* __restrict__ W2,    const float* __restrict__ b2,
    const float* __restrict__ wihT,  const f16* __restrict__ wsB,
    float* __restrict__ out)
{
    __shared__ __align__(16) f16   sA[BT * AHS];      // h | pad | static
    __shared__ __align__(16) f16   sW1[64 * AHS];
    __shared__ __align__(16) f16   sO1[16 * O1S];
    __shared__ __align__(16) f16   sW2[16 * O1S];
    __shared__ __align__(16) float sO2[16 * 8];
    __shared__ __align__(16) float sZ[TSTEPS * 32];
    __shared__ __align__(16) float sOUT[TSTEPS * 16 * 8];   // mu0,mu1,m00,m01,m11,x0,x1,pad
    __shared__ __align__(16) float sXC[32];
    __shared__ __align__(16) float sXP[32];
    __shared__ __align__(16) float sDX[32];

    const int t  = threadIdx.x;
    const int w  = t >> 6;
    const int l  = t & 63;
    const int lr = l & 15;
    const int lq = l >> 4;

    // triple ownership: w0-3 -> {w}; w4 -> none; w5 -> {4,5}; w6 -> {6,7}; w7 -> {8,9}
    int ntr = 0, tr0 = 0;
    if (w < 4)       { ntr = 1; tr0 = w; }
    else if (w >= 5) { ntr = 2; tr0 = 4 + (w - 5) * 2; }

    // ---- one-time LDS init ----
    for (int i = t; i < BT * AHS / 2; i += NT) ((unsigned*)sA)[i] = 0u;
    for (int i = t; i < 64 * AHS; i += NT) {
        int r = i / AHS, k = i - r * AHS;
        float v = 0.f;
        if (r < SD && k < 224) {
            if (k < H) v = W1[r * 200 + k];
            else if (k >= HP && k < HP + SD) v = W1[r * 200 + H + (k - HP)];
        }
        sW1[i] = (f16)v;
    }
    for (int i = t; i < 16 * O1S; i += NT) {
        int r = i / O1S, k = i - r * O1S;
        sW2[i] = (f16)((r < 6 && k < SD) ? W2[r * SD + k] : 0.f);
        sO1[i] = (f16)0.f;
    }

    // ---- one-time register loads ----
    f16x8 bfrag[2][3][5];
    #pragma unroll
    for (int tt = 0; tt < 2; ++tt) {
        if (tt < ntr) {
            int k = tr0 + tt;
            #pragma unroll
            for (int g = 0; g < 3; ++g)
                #pragma unroll
                for (int kk = 0; kk < 5; ++kk)
                    bfrag[tt][g][kk] = *(const f16x8*)(wsB + ((size_t)((k * 3 + g) * 5 + kk) * 64 + l) * 8);
        }
    }
    float cR[2], cZ[2], cNi[2], cNh[2];
    #pragma unroll
    for (int tt = 0; tt < 2; ++tt) {
        cR[tt] = cZ[tt] = cNi[tt] = cNh[tt] = 0.f;
        if (tt < ntr) {
            int u = (tr0 + tt) * 16 + lr;
            if (u < H) {
                cR[tt]  = bih[u]         + bhh[u];
                cZ[tt]  = bih[H + u]     + bhh[H + u];
                cNi[tt] = bih[2 * H + u];
                cNh[tt] = bhh[2 * H + u];
            }
        }
    }
    const int   p3col  = w * 16 + lr;
    const float b1reg  = (w < 4 && p3col < SD) ? b1[p3col] : 0.f;
    const float b2reg  = (lr < 6) ? b2[lr] : 0.f;

    float hreg[2][4];
    f32x4 acc[2][3];
    f32x4 gi[2][3];
    float2 wvp[2][3];   // prefetched W_ih columns for next step's gi update

    for (int grp = 0; grp < NGRP; ++grp) {
        const int bg0 = (grp * NBLK + blockIdx.x) * BT;
        __syncthreads();   // previous group fully done (incl. flush) before LDS reuse
        // per-group LDS init
        for (int i = t; i < BT * SD; i += NT) {
            int b = i / SD, k = i - b * SD;
            sA[b * AHS + HP + k] = (f16)statp[(bg0 + b) * SD + k];
        }
        for (int i = t; i < TSTEPS * 32; i += NT)
            sZ[i] = zp[((size_t)(i >> 5) * BTOT + bg0) * 2 + (i & 31)];
        if (t < 2 * BT) {
            sXP[t] = initp[bg0 * 2 + t];
            sDX[t] = initv[bg0 * 2 + t];
        }
        // per-group register init
        #pragma unroll
        for (int tt = 0; tt < 2; ++tt) {
            #pragma unroll
            for (int j = 0; j < 4; ++j) hreg[tt][j] = 0.f;
            #pragma unroll
            for (int g = 0; g < 3; ++g) acc[tt][g] = (f32x4){0.f, 0.f, 0.f, 0.f};
            gi[tt][0] = (f32x4){cR[tt],  cR[tt],  cR[tt],  cR[tt]};
            gi[tt][1] = (f32x4){cZ[tt],  cZ[tt],  cZ[tt],  cZ[tt]};
            gi[tt][2] = (f32x4){cNi[tt], cNi[tt], cNi[tt], cNi[tt]};
        }
        __syncthreads();

        for (int s = 0; s < TSTEPS; ++s) {
            // ---- B0: gi rank-2 update (s>0, weights prefetched) + gates ----
            if (ntr > 0) {
                if (s > 0) {
                    f32x4 xa = *(const f32x4*)&sXC[lq * 8];
                    f32x4 xb = *(const f32x4*)&sXC[lq * 8 + 4];
                    #pragma unroll
                    for (int tt = 0; tt < 2; ++tt) {
                        if (tt < ntr) {
                            #pragma unroll
                            for (int g = 0; g < 3; ++g) {
                                float2 wv = wvp[tt][g];
                                gi[tt][g][0] = fmaf(wv.x, xa[0], fmaf(wv.y, xa[1], gi[tt][g][0]));
                                gi[tt][g][1] = fmaf(wv.x, xa[2], fmaf(wv.y, xa[3], gi[tt][g][1]));
                                gi[tt][g][2] = fmaf(wv.x, xb[0], fmaf(wv.y, xb[1], gi[tt][g][2]));
                                gi[tt][g][3] = fmaf(wv.x, xb[2], fmaf(wv.y, xb[3], gi[tt][g][3]));
                            }
                        }
                    }
                }
                #pragma unroll
                for (int tt = 0; tt < 2; ++tt) {
                    if (tt < ntr) {
                        int u = (tr0 + tt) * 16 + lr;
                        #pragma unroll
                        for (int j = 0; j < 4; ++j) {
                            float r  = sigm(acc[tt][0][j] + gi[tt][0][j]);
                            float zg = sigm(acc[tt][1][j] + gi[tt][1][j]);
                            float n  = tanh_(gi[tt][2][j] + r * (acc[tt][2][j] + cNh[tt]));
                            float hv = (1.f - zg) * n + zg * hreg[tt][j];
                            hreg[tt][j] = hv;
                            if (u < H) sA[(lq * 4 + j) * AHS + u] = (f16)hv;
                        }
                    }
                }
            }
            __syncthreads();

            // prefetch next step's W_ih columns (independent of LDS state;
            // latency hides behind B1 MFMAs + barrier + B2)
            if (ntr > 0 && s + 1 < TSTEPS) {
                const float* wT = wihT + (size_t)s * (NP * 2);
                #pragma unroll
                for (int tt = 0; tt < 2; ++tt) {
                    if (tt < ntr) {
                        int u = (tr0 + tt) * 16 + lr;
                        #pragma unroll
                        for (int g = 0; g < 3; ++g)
                            wvp[tt][g] = *(const float2*)(wT + (g * HP + u) * 2);
                    }
                }
            }

            // ---- B1: w0-3: MLP1 MFMA ; w5-7: next-step recurrent MFMA ----
            if (w < 4) {
                f32x4 a3 = (f32x4){0.f, 0.f, 0.f, 0.f};
                #pragma unroll
                for (int kk = 0; kk < 7; ++kk) {
                    f16x8 av = *(const f16x8*)(sA  + lr    * AHS + kk * 32 + lq * 8);
                    f16x8 bv = *(const f16x8*)(sW1 + p3col * AHS + kk * 32 + lq * 8);
                    a3 = __builtin_amdgcn_mfma_f32_16x16x32_f16(av, bv, a3, 0, 0, 0);
                }
                if (p3col < SD) {
                    #pragma unroll
                    for (int j = 0; j < 4; ++j)
                        sO1[(lq * 4 + j) * O1S + p3col] = (f16)softplus_(a3[j] + b1reg);
                }
            } else if (w >= 5 && s + 1 < TSTEPS) {
                f16x8 af[5];
                #pragma unroll
                for (int kk = 0; kk < 5; ++kk)
                    af[kk] = *(const f16x8*)(sA + lr * AHS + kk * 32 + lq * 8);
                #pragma unroll
                for (int tt = 0; tt < 2; ++tt) {
                    #pragma unroll
                    for (int g = 0; g < 3; ++g) {
                        acc[tt][g] = (f32x4){0.f, 0.f, 0.f, 0.f};
                        #pragma unroll
                        for (int kk = 0; kk < 5; ++kk)
                            acc[tt][g] = __builtin_amdgcn_mfma_f32_16x16x32_f16(af[kk], bfrag[tt][g][kk], acc[tt][g], 0, 0, 0);
                    }
                }
            }
            __syncthreads();

            // ---- B2: w4: MLP2 + expm + stage ; w0-3: next-step MFMA ----
            if (w == 4) {
                f32x4 a4 = (f32x4){0.f, 0.f, 0.f, 0.f};
                #pragma unroll
                for (int kk = 0; kk < 2; ++kk) {
                    f16x8 av = *(const f16x8*)(sO1 + lr * O1S + kk * 32 + lq * 8);
                    f16x8 bv = *(const f16x8*)(sW2 + lr * O1S + kk * 32 + lq * 8);
                    a4 = __builtin_amdgcn_mfma_f32_16x16x32_f16(av, bv, a4, 0, 0, 0);
                }
                if (lr < 6) {
                    #pragma unroll
                    for (int j = 0; j < 4; ++j)
                        sO2[(lq * 4 + j) * 8 + lr] = softplus_(a4[j] + b2reg);
                }
                asm volatile("s_waitcnt lgkmcnt(0)" ::: "memory");
                if (l < BT) {
                    const int b = l;
                    f32x4  v0 = *(const f32x4*)&sO2[b * 8];
                    float2 v1 = *(const float2*)&sO2[b * 8 + 4];
                    float mh0 = v0[0], mh1 = v0[1];
                    float a = 2.f * v0[2], bb2 = v0[3] + v1.x, c = 2.f * v1.y;
                    float htr = 0.5f * (a + c), hdf = 0.5f * (a - c);
                    float disc = sqrtf(hdf * hdf + bb2 * bb2);
                    float d = fmaxf(disc, 1e-12f);
                    float ep = fexp(d), em = fexp(-d);
                    float sinhc = (0.5f * (ep - em)) * __builtin_amdgcn_rcpf(d);
                    float coshd = 0.5f * (ep + em);
                    float scale = fexp(htr);
                    float m00 = scale * (coshd + sinhc * hdf);
                    float m11 = scale * (coshd - sinhc * hdf);
                    float m01 = scale * (sinhc * bb2);

                    float z0 = sZ[s * 32 + 2 * b], z1 = sZ[s * 32 + 2 * b + 1];
                    float xp0 = sXP[2 * b], xp1 = sXP[2 * b + 1];
                    float mu0 = xp0 + sDX[2 * b]     + mh0;
                    float mu1 = xp1 + sDX[2 * b + 1] + mh1;
                    float x0 = fmaf(m00, z0, fmaf(m01, z1, mu0));
                    float x1 = fmaf(m01, z0, fmaf(m11, z1, mu1));

                    float* st = &sOUT[(s * 16 + b) * 8];
                    *(float4*)(st)     = make_float4(mu0, mu1, m00, m01);
                    *(float4*)(st + 4) = make_float4(m11, x0, x1, 0.f);

                    sXC[2 * b] = x0;       sXC[2 * b + 1] = x1;
                    sDX[2 * b] = x0 - xp0; sDX[2 * b + 1] = x1 - xp1;
                    sXP[2 * b] = x0;       sXP[2 * b + 1] = x1;
                }
            } else if (w < 4 && s + 1 < TSTEPS) {
                f16x8 af[5];
                #pragma unroll
                for (int kk = 0; kk < 5; ++kk)
                    af[kk] = *(const f16x8*)(sA + lr * AHS + kk * 32 + lq * 8);
                #pragma unroll
                for (int g = 0; g < 3; ++g) {
                    acc[0][g] = (f32x4){0.f, 0.f, 0.f, 0.f};
                    #pragma unroll
                    for (int kk = 0; kk < 5; ++kk)
                        acc[0][g] = __builtin_amdgcn_mfma_f32_16x16x32_f16(af[kk], bfrag[0][g][kk], acc[0][g], 0, 0, 0);
                }
            }
            __syncthreads();
        }

        // ---- group flush: coalesced output writes (one store drain/group) ----
        if (t < TSTEPS * 16) {
            int s = t >> 4, b = t & 15;
            const float* src = &sOUT[(s * 16 + b) * 8];
            const size_t oi = (size_t)s * BTOT + bg0 + b;
            *(float2*)(out + oi * 2)           = make_float2(src[0], src[1]);
            *(float4*)(out + SIG_OFF + oi * 4) = make_float4(src[2], src[3], src[3], src[4]);
            *(float2*)(out + X_OFF + oi * 2)   = make_float2(src[5], src[6]);
        }
    }
}

extern "C" void kernel_launch(void* const* d_in, const int* in_sizes, int n_in,
                              void* d_out, int out_size, void* d_ws, size_t ws_size,
                              hipStream_t stream) {
    const float* statp = (const float*)d_in[0];
    const float* initv = (const float*)d_in[1];
    const float* initp = (const float*)d_in[2];
    const float* zp    = (const float*)d_in[3];
    const float* Wih   = (const float*)d_in[4];
    const float* Whh   = (const float*)d_in[5];
    const float* bih   = (const float*)d_in[6];
    const float* bhh   = (const float*)d_in[7];
    const float* W1    = (const float*)d_in[8];
    const float* b1    = (const float*)d_in[9];
    const float* W2    = (const float*)d_in[10];
    const float* b2    = (const float*)d_in[11];
    float* out  = (float*)d_out;
    float* wihT = (float*)((char*)d_ws + WS_WIHT);
    f16*   wsB  = (f16*)  ((char*)d_ws + WS_BFRAG);

    r2p2_prep <<<(TSTEPS * NP + 255) / 256, 256, 0, stream>>>(Wih, wihT);
    r2p2_prep2<<<(9600 + 255) / 256, 256, 0, stream>>>(Whh, wsB);
    r2p2_main<<<NBLK, NT, 0, stream>>>(
        statp, initv, initp, zp, bih, bhh, W1, b1, W2, b2, wihT, wsB, out);
}